// Round 5
// baseline (143.033 us; speedup 1.0000x reference)
//
#include <hip/hip_runtime.h>

// MultiAgentLinearLayer via bf16 MFMA, round 5: occupancy-first split design.
// out[b,o] = sum_k W[agent[b],o,k]*x[b,k] + bias[agent[b],o]
// B=2048, I=O=512, 64 agents, fp32 in/out. Threshold 5.97e-2 permits bf16.
//
// R2-R4 plateau ~28-35us with <=16 of 32 wave slots/CU used (LDS-capped).
// This round strips all per-block serial work into a prologue and shrinks
// LDS so 4-8 blocks co-reside per CU:
//  kernel 1 (prologue, 128 blocks):
//    - blocks 0..63: stable per-agent row compaction -> d_ws (counts + lists)
//    - blocks 64..127: out[b,:] = bias[which[b],:]  (split-K partials can
//      then atomicAdd; harness poisons out each launch so init is mandatory)
//  kernel 2 (GEMM, 1024 blocks = 8 ntiles x 64 agents x 2 k-halves, 256 thr):
//    - 4 waves, one 16-col n-subtile each; MCH=32 rows; K-half = 256.
//    - Xs = 32 x 264 bf16 = 17 KB LDS; __launch_bounds__(256,8) -> VGPR<=64
//      -> up to 8 blocks/CU; grid avg 4/CU = 16-32 waves/CU (2-4x R2/R4).
//    - W global->register, 2-deep prefetch, converted fp32->bf16 in flight;
//      W read from HBM exactly once (disjoint 64x256 slab per block).
//    - epilogue: global_atomic_add_f32 onto bias-initialized out.

constexpr int BATCH  = 2048;
constexpr int NAGENT = 64;
constexpr int IN_F   = 512;
constexpr int OUT_F  = 512;

constexpr int BN  = 64;         // n-tile per block
constexpr int KH  = 256;        // k per block (split 2)
constexpr int MCH = 32;         // m rows per chunk
constexpr int XS  = KH + 8;     // 264 bf16 elems; stride%32(dwords)==4 -> minimal bank passes

// ws layout: [0,256): int counts[64]; [1024, 1024+64*2048*4): int rowlists
#define WS_CNT(ws)  ((int*)(ws))
#define WS_ROW(ws)  ((int*)((char*)(ws) + 1024))

typedef __attribute__((ext_vector_type(8))) short short8;     // bf16 frag (4 VGPRs)
typedef __attribute__((ext_vector_type(4))) float f32x4;      // fp32 C/D frag
typedef __attribute__((ext_vector_type(4))) unsigned int u32x4;

__device__ inline unsigned rnd_bf(float f) {
  unsigned u = __float_as_uint(f);
  return u + 0x7FFFu + ((u >> 16) & 1u);   // RTN, result in high 16 bits
}
__device__ inline unsigned pk_bf(float lo, float hi) {
  return (rnd_bf(lo) >> 16) | (rnd_bf(hi) & 0xFFFF0000u);
}

__global__ __launch_bounds__(256) void prologue(
    const int*   __restrict__ which,
    const float* __restrict__ bias,
    float*       __restrict__ out,
    int*         __restrict__ wscnt,
    int*         __restrict__ wsrow) {
  const int bid = blockIdx.x;
  const int tid = threadIdx.x;
  if (bid < NAGENT) {
    // ---- stable compaction for agent=bid ----
    const int agent = bid;
    const int lane = tid & 63, wid = tid >> 6;
    __shared__ int wsum_s[4];
    int vals[8];
    {
      const int4* w4 = (const int4*)which;
      int4 v0 = w4[tid * 2];
      int4 v1 = w4[tid * 2 + 1];
      vals[0] = v0.x; vals[1] = v0.y; vals[2] = v0.z; vals[3] = v0.w;
      vals[4] = v1.x; vals[5] = v1.y; vals[6] = v1.z; vals[7] = v1.w;
    }
    int lc = 0;
#pragma unroll
    for (int u = 0; u < 8; ++u) lc += (vals[u] == agent) ? 1 : 0;
    int s = lc;
#pragma unroll
    for (int off = 1; off < 64; off <<= 1) {
      int t = __shfl_up(s, off);
      if (lane >= off) s += t;
    }
    if (lane == 63) wsum_s[wid] = s;
    __syncthreads();
    int base = 0, count = 0;
#pragma unroll
    for (int w = 0; w < 4; ++w) {
      int ws = wsum_s[w];
      if (w < wid) base += ws;
      count += ws;
    }
    int pos = base + s - lc;
#pragma unroll
    for (int u = 0; u < 8; ++u)
      if (vals[u] == agent) wsrow[agent * BATCH + pos++] = tid * 8 + u;
    if (tid == 0) wscnt[agent] = count;
  } else {
    // ---- out[b,:] = bias[which[b],:] for 32 rows ----
    const int row = (bid - NAGENT) * 32 + (tid >> 3);
    const int a   = which[row];
    const float4* bp = (const float4*)(bias + (size_t)a * OUT_F);
    float4*       op = (float4*)(out + (size_t)row * OUT_F);
#pragma unroll
    for (int c = tid & 7; c < OUT_F / 4; c += 8) op[c] = bp[c];
  }
}

__global__ __launch_bounds__(256, 8) void agent_linear_v5(
    const float* __restrict__ x,
    const float* __restrict__ weight,
    float*       __restrict__ out,
    const int*   __restrict__ wscnt,
    const int*   __restrict__ wsrow) {
  const int tid   = threadIdx.x;
  const int lane  = tid & 63;
  const int wid   = tid >> 6;          // 0..3 n-subtile
  const int nt    = blockIdx.x;        // 0..7
  const int agent = blockIdx.y;        // 0..63
  const int kh    = blockIdx.z;        // 0..1 k-half
  const int obase = nt * BN;
  const int count = wscnt[agent];
  const int* rl   = wsrow + agent * BATCH;

  __shared__ __align__(16) unsigned short Xs[MCH * XS];   // 16.9 KB

  const int nl = lane & 15;            // n within frag / m within A-frag
  const int kq = lane >> 4;            // k-quad 0..3

  const float* wp = weight + ((size_t)(agent * OUT_F + obase + wid * 16 + nl)) * IN_F
                  + kh * KH + kq * 8;

  for (int m0 = 0; m0 < count; m0 += MCH) {
    const int mcount = min(MCH, count - m0);
    __syncthreads();   // prior chunk's Xs reads done

    // ---- stage X chunk: mcount rows x 256 k as bf16 (2048 float4 / 256 thr) ----
#pragma unroll
    for (int t = 0; t < 8; ++t) {
      int idx = t * 256 + tid;
      int r   = idx >> 6;              // row, uniform per 64-thread group
      int c4  = idx & 63;              // float4 column within k-half
      if (r < mcount) {
        float4 xv = *(const float4*)(x + (size_t)rl[m0 + r] * IN_F + kh * KH + c4 * 4);
        uint2 w2;
        w2.x = pk_bf(xv.x, xv.y);
        w2.y = pk_bf(xv.z, xv.w);
        *(uint2*)&Xs[r * XS + c4 * 4] = w2;
      }
    }
    __syncthreads();

    // ---- barrier-free K-loop: 8 chunks of 32k, 2-deep W prefetch ----
    f32x4 acc[2] = {{0.f, 0.f, 0.f, 0.f}, {0.f, 0.f, 0.f, 0.f}};
    float4 pa[2], pb[2];
    pa[0] = *(const float4*)(wp);      pb[0] = *(const float4*)(wp + 4);
    pa[1] = *(const float4*)(wp + 32); pb[1] = *(const float4*)(wp + 36);
#pragma unroll
    for (int k = 0; k < 8; ++k) {
      float4 c0 = pa[k & 1], c1 = pb[k & 1];
      if (k + 2 < 8) {
        pa[k & 1] = *(const float4*)(wp + (k + 2) * 32);
        pb[k & 1] = *(const float4*)(wp + (k + 2) * 32 + 4);
      }
      u32x4 q;
      q[0] = pk_bf(c0.x, c0.y); q[1] = pk_bf(c0.z, c0.w);
      q[2] = pk_bf(c1.x, c1.y); q[3] = pk_bf(c1.z, c1.w);
      short8 bf = __builtin_bit_cast(short8, q);
#pragma unroll
      for (int i = 0; i < 2; ++i) {
        short8 af = *(const short8*)&Xs[(i * 16 + nl) * XS + k * 32 + kq * 8];
        acc[i] = __builtin_amdgcn_mfma_f32_16x16x32_bf16(af, bf, acc[i], 0, 0, 0);
      }
    }

    // ---- epilogue: atomicAdd partial onto bias-initialized out ----
    // D layout: row = kq*4 + reg (+16*i), col = nl
#pragma unroll
    for (int i = 0; i < 2; ++i) {
#pragma unroll
      for (int r = 0; r < 4; ++r) {
        int m = i * 16 + kq * 4 + r;
        if (m < mcount) {
          atomicAdd(out + (size_t)rl[m0 + m] * OUT_F + obase + wid * 16 + nl,
                    acc[i][r]);
        }
      }
    }
  }
}

extern "C" void kernel_launch(void* const* d_in, const int* in_sizes, int n_in,
                              void* d_out, int out_size, void* d_ws, size_t ws_size,
                              hipStream_t stream) {
  const int*   which = (const int*)d_in[0];
  const float* x     = (const float*)d_in[1];
  const float* w     = (const float*)d_in[2];
  const float* b     = (const float*)d_in[3];
  float*       out   = (float*)d_out;
  int*         cnt   = WS_CNT(d_ws);
  int*         row   = WS_ROW(d_ws);

  prologue<<<dim3(128), dim3(256), 0, stream>>>(which, b, out, cnt, row);
  agent_linear_v5<<<dim3(8, 64, 2), dim3(256), 0, stream>>>(x, w, out, cnt, row);
}

// Round 6
// 114.738 us; speedup vs baseline: 1.2466x; 1.2466x over previous
//
#include <hip/hip_runtime.h>

// MultiAgentLinearLayer, round 6: linearized W stream through LDS.
// out[b,o] = sum_k W[agent[b],o,k]*x[b,k] + bias[agent[b],o]
// B=2048, I=O=512, 64 agents, fp32 in/out. Threshold 5.97e-2 permits bf16.
//
// R2-R5 all plateau at ~2.2-3.1 TB/s with the per-lane 2KB-strided 16-row
// W gather (forced by register-direct MFMA B-frags), while the harness's
// linear fill kernel does 6.5 TB/s. Fix: stream W lane-LINEAR (lane i reads
// base+i*16B) into LDS, converting fp32->bf16 and scattering into a
// frag-slot layout so each MFMA B-frag is ONE conflict-free ds_read_b128.
//  - block: 256 thr (4 waves) owns agent x 64 contiguous W rows (128 KB);
//    grid 8 x 64 = 512 blocks (2/CU). W read from HBM exactly once.
//  - W in 4 groups of 16 rows (32 KB fp32), double-buffered LDS (bf16,
//    slice stride 260 dw: B-frag read banks = 4*(lane+i)%32 -> floor).
//  - X (4 MB, L2-warm): loaded once per block into registers as bf16
//    A-frags (64 VGPRs/lane). No X LDS, no A-side ds_read.
//  - wave wv owns m-tile [wv*16, wv*16+16); waves beyond count still stage.
//  - 1 barrier per group; no atomics; bias added at store.

constexpr int BATCH  = 2048;
constexpr int NAGENT = 64;
constexpr int IN_F   = 512;
constexpr int OUT_F  = 512;

constexpr int BN    = 64;           // n-rows per block
constexpr int GR    = 16;           // n-rows per streamed group
constexpr int NG    = BN / GR;      // 4 groups
constexpr int MCH   = 64;           // m rows per chunk
constexpr int SLICE = 260;          // dwords per k-slice in Wb (256 + 4 pad)
constexpr int WBUF  = 16 * SLICE;   // 4160 dwords per group buffer (16.6 KB)

typedef __attribute__((ext_vector_type(8))) short short8;   // bf16 frag (4 VGPRs)
typedef __attribute__((ext_vector_type(4))) float f32x4;    // fp32 C/D frag
typedef __attribute__((ext_vector_type(4))) unsigned int u32x4;

__device__ inline unsigned rnd_bf(float f) {
  unsigned u = __float_as_uint(f);
  return u + 0x7FFFu + ((u >> 16) & 1u);   // RTN, result in high 16 bits
}
__device__ inline unsigned pk_bf(float lo, float hi) {
  return (rnd_bf(lo) >> 16) | (rnd_bf(hi) & 0xFFFF0000u);
}

__global__ __launch_bounds__(256, 2) void agent_linear_v6(
    const int*   __restrict__ which,
    const float* __restrict__ x,
    const float* __restrict__ weight,
    const float* __restrict__ bias,
    float*       __restrict__ out) {
  const int tid   = threadIdx.x;
  const int lane  = tid & 63;
  const int wv    = tid >> 6;        // 0..3 (wave = m-tile)
  const int agent = blockIdx.y;
  const int obase = blockIdx.x * BN;

  __shared__ int wsum_s[4];
  __shared__ int rowlist_s[BATCH];                    // 8 KB
  __shared__ __align__(16) unsigned Wb[2][WBUF];      // 33.3 KB

  // ---- stable compaction (proven R4 code): rows with which[i]==agent ----
  int vals[8];
  {
    const int4* w4 = (const int4*)which;
    int4 v0 = w4[tid * 2];
    int4 v1 = w4[tid * 2 + 1];
    vals[0] = v0.x; vals[1] = v0.y; vals[2] = v0.z; vals[3] = v0.w;
    vals[4] = v1.x; vals[5] = v1.y; vals[6] = v1.z; vals[7] = v1.w;
  }
  int lc = 0;
#pragma unroll
  for (int u = 0; u < 8; ++u) lc += (vals[u] == agent) ? 1 : 0;
  int s = lc;
#pragma unroll
  for (int off = 1; off < 64; off <<= 1) {
    int t = __shfl_up(s, off);
    if (lane >= off) s += t;
  }
  if (lane == 63) wsum_s[wv] = s;
  __syncthreads();
  int base = 0, count = 0;
#pragma unroll
  for (int w = 0; w < 4; ++w) {
    int ws = wsum_s[w];
    if (w < wv) base += ws;
    count += ws;
  }
  {
    int pos = base + s - lc;
#pragma unroll
    for (int u = 0; u < 8; ++u)
      if (vals[u] == agent) rowlist_s[pos++] = tid * 8 + u;
  }
  __syncthreads();   // rowlist_s ready

  const int nl = lane & 15;          // frag col (n) / A-frag row (m)
  const int kq = lane >> 4;          // k-quad 0..3

  float bv[NG];
#pragma unroll
  for (int g = 0; g < NG; ++g)
    bv[g] = bias[agent * OUT_F + obase + g * 16 + nl];

  // this block's contiguous 64-row W slab; per-thread linear stream base
  const float* wblk = weight + ((size_t)agent * OUT_F + obase) * IN_F;
  const float* wthr = wblk + tid * 4;   // + g*8192 + j*1024 (dwords)

  // ds_write dest (dword offset into a group buffer) for each round j:
  // linear off j*1024+tid*4 -> row r (0..15), k kk; frag slot L'=q*16+r,
  // slice i=kk/32, half h = (kk&4)>>1. Same for every group.
  int wdest[8];
#pragma unroll
  for (int j = 0; j < 8; ++j) {
    int off = j * 1024 + tid * 4;
    int r = off >> 9, kk = off & 511;
    int i = kk >> 5, q = (kk >> 3) & 3, h = (kk & 4) >> 1;
    wdest[j] = i * SLICE + (q * 16 + r) * 4 + h;
  }

  for (int m0 = 0; m0 < count; m0 += MCH) {
    const int mcount = min(MCH, count - m0);
    const bool active = (wv * 16 < mcount);   // wave-uniform

    // ---- issue W group-0 stream first (lane-linear, 8 float4 in flight) ----
    float4 wst[8];
#pragma unroll
    for (int j = 0; j < 8; ++j) wst[j] = *(const float4*)(wthr + j * 1024);

    // ---- A-frags: this wave's 16 m-rows, full K, from global (L2-warm) ----
    short8 af[16];
    if (active) {
      int mr = m0 + wv * 16 + nl;
      int myrow = rowlist_s[mr < count ? mr : m0];   // clamp; result unguarded-> store-guarded
      const float* xr = x + (size_t)myrow * IN_F + kq * 8;
#pragma unroll
      for (int i = 0; i < 16; ++i) {
        float4 a0 = *(const float4*)(xr + i * 32);
        float4 a1 = *(const float4*)(xr + i * 32 + 4);
        u32x4 uu;
        uu[0] = pk_bf(a0.x, a0.y); uu[1] = pk_bf(a0.z, a0.w);
        uu[2] = pk_bf(a1.x, a1.y); uu[3] = pk_bf(a1.z, a1.w);
        af[i] = __builtin_bit_cast(short8, uu);
      }
    }

    // ---- convert + scatter group 0 into Wb[0] ----
#pragma unroll
    for (int j = 0; j < 8; ++j) {
      uint2 p;
      p.x = pk_bf(wst[j].x, wst[j].y);
      p.y = pk_bf(wst[j].z, wst[j].w);
      *(uint2*)&Wb[0][wdest[j]] = p;
    }
    __syncthreads();

    // ---- group pipeline: stream g+1 while MFMA-ing g ----
#pragma unroll
    for (int g = 0; g < NG; ++g) {
      if (g + 1 < NG) {
#pragma unroll
        for (int j = 0; j < 8; ++j)
          wst[j] = *(const float4*)(wthr + (g + 1) * 8192 + j * 1024);
      }
      if (active) {
        f32x4 acc = {0.f, 0.f, 0.f, 0.f};
#pragma unroll
        for (int i = 0; i < 16; ++i) {
          short8 bf = *(const short8*)&Wb[g & 1][i * SLICE + lane * 4];
          acc = __builtin_amdgcn_mfma_f32_16x16x32_bf16(af[i], bf, acc, 0, 0, 0);
        }
        // D layout: row = kq*4 + r, col = nl
#pragma unroll
        for (int r = 0; r < 4; ++r) {
          int m = wv * 16 + kq * 4 + r;
          if (m < mcount)
            out[(size_t)rowlist_s[m0 + m] * OUT_F + obase + g * 16 + nl] =
                acc[r] + bv[g];
        }
      }
      if (g + 1 < NG) {
#pragma unroll
        for (int j = 0; j < 8; ++j) {
          uint2 p;
          p.x = pk_bf(wst[j].x, wst[j].y);
          p.y = pk_bf(wst[j].z, wst[j].w);
          *(uint2*)&Wb[(g + 1) & 1][wdest[j]] = p;
        }
      }
      __syncthreads();
    }
  }
}

extern "C" void kernel_launch(void* const* d_in, const int* in_sizes, int n_in,
                              void* d_out, int out_size, void* d_ws, size_t ws_size,
                              hipStream_t stream) {
  const int*   which = (const int*)d_in[0];
  const float* x     = (const float*)d_in[1];
  const float* w     = (const float*)d_in[2];
  const float* b     = (const float*)d_in[3];
  float*       out   = (float*)d_out;

  dim3 grid(OUT_F / BN, NAGENT);   // 8 x 64 = 512 blocks, 2 per CU
  agent_linear_v6<<<grid, dim3(256), 0, stream>>>(which, x, w, b, out);
}

// Round 7
// 114.101 us; speedup vs baseline: 1.2536x; 1.0056x over previous
//
#include <hip/hip_runtime.h>

// MultiAgentLinearLayer, round 7: 32 waves/CU.
// out[b,o] = sum_k W[agent[b],o,k]*x[b,k] + bias[agent[b],o]
// B=2048, I=O=512, 64 agents, fp32 in/out. Threshold 5.97e-2 permits bf16.
//
// Evidence R2-R6: perf tracks waves/CU (8w ~30-35us, 16w ~24us); layout of
// the W stream (linear vs strided gather) is irrelevant; atomics poison.
// This round doubles concurrency to 32 waves/CU:
//  - prologue (64 blocks): per-agent row compaction -> d_ws (R5-proven).
//    Removes the 8 KB rowlist + serial scan from every GEMM block.
//  - GEMM: 512 blocks (8 ntiles x 64 agents) x 1024 thr, LB(1024,8)
//    -> 2 blocks/CU x 16 waves = 32 waves/CU.
//    wave (ns,ks) owns a DISJOINT W slab: rows [obase+ns*16,+16) x
//    k [ks*128,+128) -> W converted once, read from HBM exactly once.
//    MCH=32 rows/chunk (count~32 -> one chunk). Xs 33 KB + Rs 28 KB = 61 KB
//    -> 2 blocks/CU. k-quarter partials reduced through Rs (stride-17 pad:
//    max 2-way bank aliasing = free). No atomics; bias at final store.

constexpr int BATCH  = 2048;
constexpr int NAGENT = 64;
constexpr int IN_F   = 512;
constexpr int OUT_F  = 512;

constexpr int BN  = 64;          // n-cols per block
constexpr int MCH = 32;          // m rows per chunk
constexpr int XS  = IN_F + 8;    // Xs stride in bf16 elems (520) — measured 0-conflict

#define WS_CNT(ws)  ((int*)(ws))
#define WS_ROW(ws)  ((int*)((char*)(ws) + 1024))

typedef __attribute__((ext_vector_type(8))) short short8;   // bf16 frag (4 VGPRs)
typedef __attribute__((ext_vector_type(4))) float f32x4;    // fp32 C/D frag
typedef __attribute__((ext_vector_type(4))) unsigned int u32x4;

__device__ inline unsigned rnd_bf(float f) {
  unsigned u = __float_as_uint(f);
  return u + 0x7FFFu + ((u >> 16) & 1u);   // RTN, result in high 16 bits
}
__device__ inline unsigned pk_bf(float lo, float hi) {
  return (rnd_bf(lo) >> 16) | (rnd_bf(hi) & 0xFFFF0000u);
}

__global__ __launch_bounds__(256) void prologue(
    const int* __restrict__ which,
    int*       __restrict__ wscnt,
    int*       __restrict__ wsrow) {
  const int agent = blockIdx.x;
  const int tid   = threadIdx.x;
  const int lane  = tid & 63, wid = tid >> 6;
  __shared__ int wsum_s[4];
  int vals[8];
  {
    const int4* w4 = (const int4*)which;
    int4 v0 = w4[tid * 2];
    int4 v1 = w4[tid * 2 + 1];
    vals[0] = v0.x; vals[1] = v0.y; vals[2] = v0.z; vals[3] = v0.w;
    vals[4] = v1.x; vals[5] = v1.y; vals[6] = v1.z; vals[7] = v1.w;
  }
  int lc = 0;
#pragma unroll
  for (int u = 0; u < 8; ++u) lc += (vals[u] == agent) ? 1 : 0;
  int s = lc;
#pragma unroll
  for (int off = 1; off < 64; off <<= 1) {
    int t = __shfl_up(s, off);
    if (lane >= off) s += t;
  }
  if (lane == 63) wsum_s[wid] = s;
  __syncthreads();
  int base = 0, count = 0;
#pragma unroll
  for (int w = 0; w < 4; ++w) {
    int ws = wsum_s[w];
    if (w < wid) base += ws;
    count += ws;
  }
  int pos = base + s - lc;
#pragma unroll
  for (int u = 0; u < 8; ++u)
    if (vals[u] == agent) wsrow[agent * BATCH + pos++] = tid * 8 + u;
  if (tid == 0) wscnt[agent] = count;
}

__global__ __launch_bounds__(1024, 8) void agent_linear_v7(
    const float* __restrict__ x,
    const float* __restrict__ weight,
    const float* __restrict__ bias,
    float*       __restrict__ out,
    const int*   __restrict__ wscnt,
    const int*   __restrict__ wsrow) {
  const int tid   = threadIdx.x;
  const int lane  = tid & 63;
  const int wid   = tid >> 6;        // 0..15
  const int ns    = wid & 3;         // n-subtile (16 cols)
  const int ks    = wid >> 2;        // k-quarter (128 k)
  const int agent = blockIdx.y;
  const int obase = blockIdx.x * BN;
  const int count = wscnt[agent];
  const int* rl   = wsrow + agent * BATCH;

  __shared__ __align__(16) unsigned short Xs[MCH * XS];   // 33.3 KB
  __shared__ float Rs[3][4][MCH][17];                     // 27.8 KB

  const int nl = lane & 15;          // frag col (n) / A-frag row (m)
  const int kq = lane >> 4;          // k-quad 0..3

  const float* wp = weight + ((size_t)(agent * OUT_F + obase + ns * 16 + nl)) * IN_F
                  + ks * 128 + kq * 8;
  const float  bv = bias[agent * OUT_F + obase + ns * 16 + nl];

  for (int m0 = 0; m0 < count; m0 += MCH) {
    const int mcount = min(MCH, count - m0);
    __syncthreads();   // prior iter's Xs/Rs reads done

    // ---- stage X chunk: mcount rows x 512 k as bf16 (4096 float4 / 1024 thr) ----
#pragma unroll
    for (int t = 0; t < 4; ++t) {
      int idx = t * 1024 + tid;
      int r   = idx >> 7;            // 0..31
      int c4  = idx & 127;           // float4 column
      if (r < mcount) {
        float4 xv = *(const float4*)(x + (size_t)rl[m0 + r] * IN_F + c4 * 4);
        uint2 w2;
        w2.x = pk_bf(xv.x, xv.y);
        w2.y = pk_bf(xv.z, xv.w);
        *(uint2*)&Xs[r * XS + c4 * 4] = w2;
      }
    }
    __syncthreads();

    // ---- K-loop over this wave's 128-k quarter: all 8 W float4 upfront ----
    float4 wv_[8];
#pragma unroll
    for (int i = 0; i < 4; ++i) {
      wv_[2 * i]     = *(const float4*)(wp + i * 32);
      wv_[2 * i + 1] = *(const float4*)(wp + i * 32 + 4);
    }
    f32x4 acc[2] = {{0.f, 0.f, 0.f, 0.f}, {0.f, 0.f, 0.f, 0.f}};
#pragma unroll
    for (int i = 0; i < 4; ++i) {
      u32x4 q;
      q[0] = pk_bf(wv_[2 * i].x,     wv_[2 * i].y);
      q[1] = pk_bf(wv_[2 * i].z,     wv_[2 * i].w);
      q[2] = pk_bf(wv_[2 * i + 1].x, wv_[2 * i + 1].y);
      q[3] = pk_bf(wv_[2 * i + 1].z, wv_[2 * i + 1].w);
      short8 bf = __builtin_bit_cast(short8, q);
#pragma unroll
      for (int mt = 0; mt < 2; ++mt) {
        short8 af = *(const short8*)&Xs[(mt * 16 + nl) * XS + ks * 128 + i * 32 + kq * 8];
        acc[mt] = __builtin_amdgcn_mfma_f32_16x16x32_bf16(af, bf, acc[mt], 0, 0, 0);
      }
    }

    // ---- k-quarter reduction through Rs ----
    // D layout: m = mt*16 + kq*4 + r, col = nl
    if (ks != 0) {
#pragma unroll
      for (int mt = 0; mt < 2; ++mt)
#pragma unroll
        for (int r = 0; r < 4; ++r)
          Rs[ks - 1][ns][mt * 16 + kq * 4 + r][nl] = acc[mt][r];
    }
    __syncthreads();
    if (ks == 0) {
#pragma unroll
      for (int mt = 0; mt < 2; ++mt) {
#pragma unroll
        for (int r = 0; r < 4; ++r) {
          int m = mt * 16 + kq * 4 + r;
          float v = acc[mt][r] + Rs[0][ns][m][nl] + Rs[1][ns][m][nl]
                  + Rs[2][ns][m][nl] + bv;
          if (m < mcount)
            out[(size_t)rl[m0 + m] * OUT_F + obase + ns * 16 + nl] = v;
        }
      }
    }
  }
}

extern "C" void kernel_launch(void* const* d_in, const int* in_sizes, int n_in,
                              void* d_out, int out_size, void* d_ws, size_t ws_size,
                              hipStream_t stream) {
  const int*   which = (const int*)d_in[0];
  const float* x     = (const float*)d_in[1];
  const float* w     = (const float*)d_in[2];
  const float* b     = (const float*)d_in[3];
  float*       out   = (float*)d_out;
  int*         cnt   = WS_CNT(d_ws);
  int*         row   = WS_ROW(d_ws);

  prologue<<<dim3(NAGENT), dim3(256), 0, stream>>>(which, cnt, row);
  agent_linear_v7<<<dim3(OUT_F / BN, NAGENT), dim3(1024), 0, stream>>>(
      x, w, b, out, cnt, row);
}